// Round 11
// baseline (368.508 us; speedup 1.0000x reference)
//
#include <hip/hip_runtime.h>

#define NNODES 50000
#define NEDGES 800000
#define F 128
#define NREL 8
#define NOUT 1152   // 9*128: 8 relations + self-loop
#define NBKT 98     // ceil(50000 / 512) coarse buckets
#define BSH 9       // 512 nodes per bucket
#define NTILES 391  // ceil(50000/128)

typedef short bf16x8 __attribute__((ext_vector_type(8)));
typedef float f32x4 __attribute__((ext_vector_type(4)));
typedef float f32x2 __attribute__((ext_vector_type(2)));

__device__ __forceinline__ unsigned f2bf(float f) {  // RNE
  unsigned u = __float_as_uint(f);
  u += 0x7fffu + ((u >> 16) & 1u);
  return u >> 16;
}
__device__ __forceinline__ float bf2f(unsigned v) {
  return __uint_as_float(v << 16);
}

// ========== fused prep: chist | cvt | prepw(W1) | prepw(W2) =================
// Block ranges partition independent work to cut dispatch count.
#define PREP_CHIST 196
#define PREP_CVT   12500   // 50000*128/2 / 256
#define PREP_W     576     // 1152*128 / 256
__global__ __launch_bounds__(256)
void k_prep(const int* __restrict__ dst, int* __restrict__ bcnt,
            const float* __restrict__ in_feat, ushort* __restrict__ feat0,
            const float* __restrict__ W1, const float* __restrict__ W1s,
            ushort* __restrict__ Wt1,
            const float* __restrict__ W2, const float* __restrict__ W2s,
            ushort* __restrict__ Wt2) {
  const int b = blockIdx.x, t = threadIdx.x;
  if (b < PREP_CHIST) {
    __shared__ int hist[NBKT];
    if (t < NBKT) hist[t] = 0;
    __syncthreads();
    int e0 = b * 4096;
#pragma unroll
    for (int i = 0; i < 16; ++i) {
      int e = e0 + t + i * 256;
      if (e < NEDGES) atomicAdd(&hist[dst[e] >> BSH], 1);
    }
    __syncthreads();
    if (t < NBKT && hist[t] > 0) atomicAdd(&bcnt[t], hist[t]);
  } else if (b < PREP_CHIST + PREP_CVT) {
    int i = (b - PREP_CHIST) * 256 + t;  // exactly 3.2M
    float2 v = ((const float2*)in_feat)[i];
    ((unsigned*)feat0)[i] = f2bf(v.x) | (f2bf(v.y) << 16);
  } else {
    int w2 = (b >= PREP_CHIST + PREP_CVT + PREP_W);
    int idx = (b - PREP_CHIST - PREP_CVT - (w2 ? PREP_W : 0)) * 256 + t;
    int n = idx >> 7, k = idx & 127;
    int r = n >> 7, c = n & 127;
    const float* Wr = w2 ? W2 : W1;
    const float* Ws = w2 ? W2s : W1s;
    float v = (r < NREL) ? Wr[((size_t)r * F + k) * F + c] : Ws[(size_t)k * F + c];
    (w2 ? Wt2 : Wt1)[idx] = (ushort)f2bf(v);
  }
}

// ================= CSR build via two-level counting sort ====================
__global__ __launch_bounds__(128)
void k_cscan(const int* __restrict__ bcnt, int* __restrict__ bbase,
             int* __restrict__ bcur, int* __restrict__ rowptr) {
  __shared__ int s[128];
  int t = threadIdx.x;
  int v = (t < NBKT) ? bcnt[t] : 0;
  s[t] = v;
  __syncthreads();
  for (int off = 1; off < 128; off <<= 1) {
    int x = (t >= off) ? s[t - off] : 0;
    __syncthreads();
    s[t] += x;
    __syncthreads();
  }
  if (t < NBKT) { bbase[t] = s[t] - v; bcur[t] = s[t] - v; }
  if (t == 0) rowptr[NNODES] = NEDGES;
}

// record = (dst_local << 19) | (src << 3) | et
__global__ __launch_bounds__(256)
void k_cscatter(const int* __restrict__ src, const int* __restrict__ dst,
                const int* __restrict__ et, int* __restrict__ bcur,
                int* __restrict__ ebuf) {
  __shared__ int lhist[NBKT];
  __shared__ int lbase[NBKT];
  int t = threadIdx.x;
  if (t < NBKT) lhist[t] = 0;
  __syncthreads();
  int e0 = blockIdx.x * 4096;
  int rec[16], cc[16], lr[16];
#pragma unroll
  for (int i = 0; i < 16; ++i) {
    int e = e0 + t + i * 256;
    if (e < NEDGES) {
      int d = dst[e];
      cc[i] = d >> BSH;
      rec[i] = ((d & 511) << 19) | (src[e] << 3) | et[e];
      lr[i] = atomicAdd(&lhist[cc[i]], 1);
    } else {
      cc[i] = -1;
    }
  }
  __syncthreads();
  if (t < NBKT && lhist[t] > 0) lbase[t] = atomicAdd(&bcur[t], lhist[t]);
  __syncthreads();
#pragma unroll
  for (int i = 0; i < 16; ++i)
    if (cc[i] >= 0) ebuf[lbase[cc[i]] + lr[i]] = rec[i];
}

__global__ __launch_bounds__(256)
void k_fsort(const int* __restrict__ ebuf, const int* __restrict__ bbase,
             const int* __restrict__ bcnt, int* __restrict__ rowptr,
             int* __restrict__ edata) {
  __shared__ int cnt[512];
  __shared__ int pos[512];
  __shared__ int ws2[256];
  const int b = blockIdx.x, t = threadIdx.x;
  const int beg = bbase[b], end = beg + bcnt[b];
  cnt[t] = 0; cnt[t + 256] = 0;
  __syncthreads();
  for (int e = beg + t; e < end; e += 256)
    atomicAdd(&cnt[((unsigned)ebuf[e]) >> 19], 1);
  __syncthreads();
  int a = cnt[2 * t], b2 = cnt[2 * t + 1];
  ws2[t] = a + b2;
  __syncthreads();
  for (int off = 1; off < 256; off <<= 1) {
    int x = (t >= off) ? ws2[t - off] : 0;
    __syncthreads();
    ws2[t] += x;
    __syncthreads();
  }
  int ep = ws2[t] - (a + b2);
  pos[2 * t] = ep;
  pos[2 * t + 1] = ep + a;
  __syncthreads();
  int node0 = b << BSH;
#pragma unroll
  for (int i = t; i < 512; i += 256) {
    int node = node0 + i;
    if (node < NNODES) rowptr[node] = beg + pos[i];
  }
  __syncthreads();
  for (int e = beg + t; e < end; e += 256) {
    int rec = ebuf[e];
    int c = ((unsigned)rec) >> 19;
    int lrank = atomicAdd(&pos[c], 1);
    int srcv = (rec >> 3) & 0xFFFF;
    int etv = rec & 7;
    edata[beg + lrank] = srcv * NOUT + etv * F;  // byte offset in fp8 xrs
  }
}

// ====== GEMM: xrs[50000][1152](fp8) = A[50000][128] @ Wt^T  (bf16 MFMA) =====
// LDS-free: each lane loads its MFMA fragments directly from global (16B
// dwordx4; a wave covers 16 rows x 64B contiguous -> L2-friendly). No barrier.
// Explicit next-chunk prefetch: 8 independent loads in flight during MFMAs.
// K-chunk accumulation order c=0..3 unchanged -> bit-identical results.
__global__ __launch_bounds__(256, 3)
void gemm_xrs(const ushort* __restrict__ A, const ushort* __restrict__ Wt,
              unsigned char* __restrict__ xrs) {
  const int id = blockIdx.x;
  const int x = id & 7, j = id >> 3;
  const int tile = (j / 9) * 8 + x;
  const int cb = j % 9;
  if (tile >= NTILES) return;
  const int row0 = tile * 128;

  const int tid = threadIdx.x;
  const int lane = tid & 63;
  const int w = tid >> 6;
  const int i16 = lane & 15, q = lane >> 4;
  const int mbase = (w & 1) * 64, nbase = (w >> 1) * 64;

  const ushort* ap[4];
  const ushort* bp[4];
#pragma unroll
  for (int mi = 0; mi < 4; ++mi) {
    int r = row0 + mbase + mi * 16 + i16;
    if (r >= NNODES) r = NNODES - 1;
    ap[mi] = A + (size_t)r * F + q * 8;
  }
#pragma unroll
  for (int ni = 0; ni < 4; ++ni) {
    int r = cb * 128 + nbase + ni * 16 + i16;
    bp[ni] = Wt + (size_t)r * F + q * 8;
  }

  f32x4 acc[4][4];
#pragma unroll
  for (int a = 0; a < 4; ++a)
#pragma unroll
    for (int b = 0; b < 4; ++b) acc[a][b] = (f32x4)0.f;

  bf16x8 aCur[4], bCur[4], aNxt[4], bNxt[4];
#pragma unroll
  for (int mi = 0; mi < 4; ++mi) aCur[mi] = *(const bf16x8*)(ap[mi]);
#pragma unroll
  for (int ni = 0; ni < 4; ++ni) bCur[ni] = *(const bf16x8*)(bp[ni]);

#pragma unroll
  for (int c = 0; c < 4; ++c) {
    if (c < 3) {
#pragma unroll
      for (int mi = 0; mi < 4; ++mi)
        aNxt[mi] = *(const bf16x8*)(ap[mi] + (c + 1) * 32);
#pragma unroll
      for (int ni = 0; ni < 4; ++ni)
        bNxt[ni] = *(const bf16x8*)(bp[ni] + (c + 1) * 32);
    }
    // Swapped operands: D[m=weight feature][n=node row]
#pragma unroll
    for (int mi = 0; mi < 4; ++mi)
#pragma unroll
      for (int ni = 0; ni < 4; ++ni)
        acc[mi][ni] = __builtin_amdgcn_mfma_f32_16x16x32_bf16(
            bCur[ni], aCur[mi], acc[mi][ni], 0, 0, 0);
#pragma unroll
    for (int mi = 0; mi < 4; ++mi) aCur[mi] = aNxt[mi];
#pragma unroll
    for (int ni = 0; ni < 4; ++ni) bCur[ni] = bNxt[ni];
  }

  // Epilogue: lane holds rows (node) = row0+mbase+mi*16+i16,
  // cols (feature) = cb*128 + nbase + ni*16 + q*4 + [0..3] -> 4 fp8 -> uint.
#pragma unroll
  for (int mi = 0; mi < 4; ++mi) {
    int row = row0 + mbase + mi * 16 + i16;
    bool ok = row < NNODES;
    size_t rb = (size_t)row * NOUT + cb * 128 + nbase + q * 4;
#pragma unroll
    for (int ni = 0; ni < 4; ++ni) {
      f32x4 v = acc[mi][ni];
      unsigned pk = 0;
      pk = __builtin_amdgcn_cvt_pk_fp8_f32(v[0], v[1], pk, false);
      pk = __builtin_amdgcn_cvt_pk_fp8_f32(v[2], v[3], pk, true);
      if (ok) *(unsigned*)(xrs + rb + ni * 16) = pk;
    }
  }
}

// ========== aggregate: h_next[dst] = relu(sum_e xrs[edata] + self + b) ======
// One wave per dst node; fp8 rows (128 B); 16 gather loads in flight.
__global__ __launch_bounds__(256)
void k_aggregate(const unsigned char* __restrict__ xrs,
                 const int* __restrict__ rowptr, const int* __restrict__ edata,
                 const float* __restrict__ bias, ushort* __restrict__ hout) {
  int node = (blockIdx.x * 256 + threadIdx.x) >> 6;
  int lane = threadIdx.x & 63;
  if (node >= NNODES) return;
  int beg = rowptr[node], end = rowptr[node + 1];

  // self-loop row (r=8)
  unsigned sv = ((const ushort*)(xrs + (size_t)node * NOUT + NREL * F))[lane];
  f32x2 sf = __builtin_amdgcn_cvt_pk_f32_fp8(sv, false);
  float ax = sf[0], ay = sf[1];

  for (int base = beg; base < end; base += 64) {
    int cnt = end - base; if (cnt > 64) cnt = 64;
    int my = (base + lane < end) ? edata[base + lane] : 0;
    int e = 0;
    for (; e + 16 <= cnt; e += 16) {
      unsigned v[16];
#pragma unroll
      for (int k = 0; k < 16; ++k)
        v[k] = ((const ushort*)(xrs + (size_t)__builtin_amdgcn_readlane(my, e + k)))[lane];
#pragma unroll
      for (int k = 0; k < 16; ++k) {
        f32x2 f = __builtin_amdgcn_cvt_pk_f32_fp8(v[k], false);
        ax += f[0]; ay += f[1];
      }
    }
    for (; e + 4 <= cnt; e += 4) {
      unsigned v[4];
#pragma unroll
      for (int k = 0; k < 4; ++k)
        v[k] = ((const ushort*)(xrs + (size_t)__builtin_amdgcn_readlane(my, e + k)))[lane];
#pragma unroll
      for (int k = 0; k < 4; ++k) {
        f32x2 f = __builtin_amdgcn_cvt_pk_f32_fp8(v[k], false);
        ax += f[0]; ay += f[1];
      }
    }
    for (; e < cnt; ++e) {
      unsigned vv = ((const ushort*)(xrs + (size_t)__builtin_amdgcn_readlane(my, e)))[lane];
      f32x2 f = __builtin_amdgcn_cvt_pk_f32_fp8(vv, false);
      ax += f[0]; ay += f[1];
    }
  }

  float2 bb = ((const float2*)bias)[lane];
  ax = fmaxf(ax + bb.x, 0.f);
  ay = fmaxf(ay + bb.y, 0.f);
  ((unsigned*)(hout + (size_t)node * F))[lane] = f2bf(ax) | (f2bf(ay) << 16);
}

// ============ mean-pool + final fc fused (completion counter) ===============
__global__ __launch_bounds__(256)
void k_colsum_fc(const ushort* __restrict__ h2, float* __restrict__ pooled,
                 unsigned* __restrict__ counter, const float* __restrict__ fcw,
                 const float* __restrict__ fcb, float* __restrict__ out) {
  __shared__ float red[4][128];
  __shared__ unsigned lastFlag;
  const int j = threadIdx.x & 63;
  const int wv = threadIdx.x >> 6;
  float sx = 0.f, sy = 0.f;
  for (int r0 = blockIdx.x * 16 + wv * 4; r0 < NNODES; r0 += gridDim.x * 16) {
    const unsigned* p = (const unsigned*)h2 + (size_t)r0 * 64 + j;
    unsigned v0 = p[0];
    unsigned v1 = (r0 + 1 < NNODES) ? p[64] : 0;
    unsigned v2 = (r0 + 2 < NNODES) ? p[128] : 0;
    unsigned v3 = (r0 + 3 < NNODES) ? p[192] : 0;
    sx += bf2f(v0 & 0xffffu) + bf2f(v1 & 0xffffu) +
          bf2f(v2 & 0xffffu) + bf2f(v3 & 0xffffu);
    sy += bf2f(v0 >> 16) + bf2f(v1 >> 16) + bf2f(v2 >> 16) + bf2f(v3 >> 16);
  }
  red[wv][2 * j] = sx;
  red[wv][2 * j + 1] = sy;
  __syncthreads();
  if (threadIdx.x < 128) {
    float s = red[0][threadIdx.x] + red[1][threadIdx.x] +
              red[2][threadIdx.x] + red[3][threadIdx.x];
    atomicAdd(&pooled[threadIdx.x], s);
  }
  __syncthreads();   // drains this block's atomics (vmcnt(0) before barrier)
  if (threadIdx.x == 0) {
    __threadfence();
    lastFlag = (atomicAdd(counter, 1u) == (unsigned)gridDim.x - 1u) ? 1u : 0u;
  }
  __syncthreads();
  if (lastFlag) {
    __shared__ float sred[128];
    int t = threadIdx.x;
    if (t < 128)  // atomic no-op add = coherent read of all blocks' sums
      sred[t] = atomicAdd(&pooled[t], 0.0f) * (1.0f / (float)NNODES) * fcw[t];
    __syncthreads();
    if (t == 0) {
      float v = 0.f;
      for (int i = 0; i < 128; ++i) v += sred[i];
      v += fcb[0];
      out[0] = 1.f / (1.f + expf(-v));
    }
  }
}

// ============================================================================
extern "C" void kernel_launch(void* const* d_in, const int* in_sizes, int n_in,
                              void* d_out, int out_size, void* d_ws, size_t ws_size,
                              hipStream_t stream) {
  const float* in_feat = (const float*)d_in[0];
  const float* W1      = (const float*)d_in[1];
  const float* W1s     = (const float*)d_in[2];
  const float* b1      = (const float*)d_in[3];
  const float* W2      = (const float*)d_in[4];
  const float* W2s     = (const float*)d_in[5];
  const float* b2      = (const float*)d_in[6];
  const float* fcw     = (const float*)d_in[7];
  const float* fcb     = (const float*)d_in[8];
  const int*   src     = (const int*)d_in[9];
  const int*   dst     = (const int*)d_in[10];
  const int*   et      = (const int*)d_in[11];
  float* out = (float*)d_out;

  // Workspace (~110 MB)
  unsigned char* xrs = (unsigned char*)d_ws;              // [50000][1152] fp8
  ushort* feat0 = (ushort*)(xrs + (size_t)NNODES * NOUT); // [50000][128] bf16
  ushort* h1    = feat0 + (size_t)NNODES * F;             // [50000][128]
  ushort* h2    = h1 + (size_t)NNODES * F;                // [50000][128]
  ushort* Wt1   = h2 + (size_t)NNODES * F;                // [1152][128]
  ushort* Wt2   = Wt1 + (size_t)NOUT * F;                 // [1152][128]
  float*    pooled  = (float*)(Wt2 + (size_t)NOUT * F);   // [128]   } one
  unsigned* counter = (unsigned*)(pooled + 128);          // [1]     } memset
  int*      bcnt    = (int*)(counter + 1);                // [NBKT]  } region
  int*   rowptr = bcnt + NBKT;                            // [NNODES+1]
  int*   bbase  = rowptr + NNODES + 2;                    // [NBKT]
  int*   bcur   = bbase + NBKT;                           // [NBKT]
  int*   ebuf   = bcur + NBKT + 1;                        // [NEDGES]
  int*   edata  = ebuf + NEDGES;                          // [NEDGES]

  // single memset: pooled + counter + bcnt
  hipMemsetAsync(pooled, 0, (128 + 1 + NBKT) * sizeof(float), stream);

  // fused prep: coarse hist | feat cvt | weight prep x2
  k_prep<<<PREP_CHIST + PREP_CVT + 2 * PREP_W, 256, 0, stream>>>(
      dst, bcnt, in_feat, feat0, W1, W1s, Wt1, W2, W2s, Wt2);
  k_cscan<<<1, 128, 0, stream>>>(bcnt, bbase, bcur, rowptr);
  k_cscatter<<<196, 256, 0, stream>>>(src, dst, et, bcur, ebuf);
  k_fsort<<<NBKT, 256, 0, stream>>>(ebuf, bbase, bcnt, rowptr, edata);

  const int gemmBlocks = 8 * 9 * 49;                   // 3528 (XCD-swizzled)
  const int aggBlocks = (NNODES * 64 + 255) / 256;     // 12500

  // Layer 1: transform then aggregate
  gemm_xrs<<<gemmBlocks, 256, 0, stream>>>(feat0, Wt1, xrs);
  k_aggregate<<<aggBlocks, 256, 0, stream>>>(xrs, rowptr, edata, b1, h1);
  // Layer 2
  gemm_xrs<<<gemmBlocks, 256, 0, stream>>>(h1, Wt2, xrs);
  k_aggregate<<<aggBlocks, 256, 0, stream>>>(xrs, rowptr, edata, b2, h2);

  // Mean-pool + fc + sigmoid (fused, completion-counter)
  k_colsum_fc<<<784, 256, 0, stream>>>(h2, pooled, counter, fcw, fcb, out);
}

// Round 12
// 297.619 us; speedup vs baseline: 1.2382x; 1.2382x over previous
//
#include <hip/hip_runtime.h>

#define NNODES 50000
#define NEDGES 800000
#define F 128
#define NREL 8
#define NOUT 1152   // 9*128: 8 relations + self-loop
#define NBKT 98     // ceil(50000 / 512) coarse buckets
#define BSH 9       // 512 nodes per bucket
#define NTILES 391  // ceil(50000/128)
#define GEMM_BLOCKS (8 * 9 * 49)   // 3528 (XCD-swizzled)
#define CSR_BLOCKS 196

typedef short bf16x8 __attribute__((ext_vector_type(8)));
typedef float f32x4 __attribute__((ext_vector_type(4)));
typedef float f32x2 __attribute__((ext_vector_type(2)));

__device__ __forceinline__ unsigned f2bf(float f) {  // RNE
  unsigned u = __float_as_uint(f);
  u += 0x7fffu + ((u >> 16) & 1u);
  return u >> 16;
}
__device__ __forceinline__ float bf2f(unsigned v) {
  return __uint_as_float(v << 16);
}

// ========== fused prep: chist | cvt | prepw(W1) | prepw(W2) =================
#define PREP_CHIST 196
#define PREP_CVT   12500   // 50000*128/2 / 256
#define PREP_W     576     // 1152*128 / 256
__global__ __launch_bounds__(256)
void k_prep(const int* __restrict__ dst, int* __restrict__ bcnt,
            const float* __restrict__ in_feat, ushort* __restrict__ feat0,
            const float* __restrict__ W1, const float* __restrict__ W1s,
            ushort* __restrict__ Wt1,
            const float* __restrict__ W2, const float* __restrict__ W2s,
            ushort* __restrict__ Wt2) {
  const int b = blockIdx.x, t = threadIdx.x;
  if (b < PREP_CHIST) {
    __shared__ int hist[NBKT];
    if (t < NBKT) hist[t] = 0;
    __syncthreads();
    int e0 = b * 4096;
#pragma unroll
    for (int i = 0; i < 16; ++i) {
      int e = e0 + t + i * 256;
      if (e < NEDGES) atomicAdd(&hist[dst[e] >> BSH], 1);
    }
    __syncthreads();
    if (t < NBKT && hist[t] > 0) atomicAdd(&bcnt[t], hist[t]);
  } else if (b < PREP_CHIST + PREP_CVT) {
    int i = (b - PREP_CHIST) * 256 + t;  // exactly 3.2M
    float2 v = ((const float2*)in_feat)[i];
    ((unsigned*)feat0)[i] = f2bf(v.x) | (f2bf(v.y) << 16);
  } else {
    int w2 = (b >= PREP_CHIST + PREP_CVT + PREP_W);
    int idx = (b - PREP_CHIST - PREP_CVT - (w2 ? PREP_W : 0)) * 256 + t;
    int n = idx >> 7, k = idx & 127;
    int r = n >> 7, c = n & 127;
    const float* Wr = w2 ? W2 : W1;
    const float* Ws = w2 ? W2s : W1s;
    float v = (r < NREL) ? Wr[((size_t)r * F + k) * F + c] : Ws[(size_t)k * F + c];
    (w2 ? Wt2 : Wt1)[idx] = (ushort)f2bf(v);
  }
}

// ================= CSR scan =================================================
__global__ __launch_bounds__(128)
void k_cscan(const int* __restrict__ bcnt, int* __restrict__ bbase,
             int* __restrict__ bcur, int* __restrict__ rowptr) {
  __shared__ int s[128];
  int t = threadIdx.x;
  int v = (t < NBKT) ? bcnt[t] : 0;
  s[t] = v;
  __syncthreads();
  for (int off = 1; off < 128; off <<= 1) {
    int x = (t >= off) ? s[t - off] : 0;
    __syncthreads();
    s[t] += x;
    __syncthreads();
  }
  if (t < NBKT) { bbase[t] = s[t] - v; bcur[t] = s[t] - v; }
  if (t == 0) rowptr[NNODES] = NEDGES;
}

__global__ __launch_bounds__(256)
void k_fsort(const int* __restrict__ ebuf, const int* __restrict__ bbase,
             const int* __restrict__ bcnt, int* __restrict__ rowptr,
             int* __restrict__ edata) {
  __shared__ int cnt[512];
  __shared__ int pos[512];
  __shared__ int ws2[256];
  const int b = blockIdx.x, t = threadIdx.x;
  const int beg = bbase[b], end = beg + bcnt[b];
  cnt[t] = 0; cnt[t + 256] = 0;
  __syncthreads();
  for (int e = beg + t; e < end; e += 256)
    atomicAdd(&cnt[((unsigned)ebuf[e]) >> 19], 1);
  __syncthreads();
  int a = cnt[2 * t], b2 = cnt[2 * t + 1];
  ws2[t] = a + b2;
  __syncthreads();
  for (int off = 1; off < 256; off <<= 1) {
    int x = (t >= off) ? ws2[t - off] : 0;
    __syncthreads();
    ws2[t] += x;
    __syncthreads();
  }
  int ep = ws2[t] - (a + b2);
  pos[2 * t] = ep;
  pos[2 * t + 1] = ep + a;
  __syncthreads();
  int node0 = b << BSH;
#pragma unroll
  for (int i = t; i < 512; i += 256) {
    int node = node0 + i;
    if (node < NNODES) rowptr[node] = beg + pos[i];
  }
  __syncthreads();
  for (int e = beg + t; e < end; e += 256) {
    int rec = ebuf[e];
    int c = ((unsigned)rec) >> 19;
    int lrank = atomicAdd(&pos[c], 1);
    int srcv = (rec >> 3) & 0xFFFF;
    int etv = rec & 7;
    edata[beg + lrank] = srcv * NOUT + etv * F;  // byte offset in fp8 xrs
  }
}

// ====== GEMM (R10 LDS version) + optional fused CSR-scatter blocks ==========
// doCsr: blocks [0,196) perform the coarse-bucket scatter; rest do GEMM.
// GEMM: full-K single-stage, XOR-swizzled LDS, one barrier, 64 MFMAs,
// fp8-packed epilogue. Bit-identical to R10.
__global__ __launch_bounds__(256)
void gemm_xrs(const ushort* __restrict__ A, const ushort* __restrict__ Wt,
              unsigned char* __restrict__ xrs, int doCsr,
              const int* __restrict__ src, const int* __restrict__ dst,
              const int* __restrict__ et, int* __restrict__ bcur,
              int* __restrict__ ebuf) {
  __shared__ uint4 As[2048];  // 128 rows x 16 uint4, xor-swizzled
  __shared__ uint4 Bs[2048];
  __shared__ int lhist[NBKT];
  __shared__ int lbase[NBKT];
  const int tid = threadIdx.x;

  if (doCsr && blockIdx.x < CSR_BLOCKS) {
    // ---- coarse scatter: record = (dst_local<<19)|(src<<3)|et ----
    if (tid < NBKT) lhist[tid] = 0;
    __syncthreads();
    int e0 = blockIdx.x * 4096;
    int rec[16], cc[16], lr[16];
#pragma unroll
    for (int i = 0; i < 16; ++i) {
      int e = e0 + tid + i * 256;
      if (e < NEDGES) {
        int d = dst[e];
        cc[i] = d >> BSH;
        rec[i] = ((d & 511) << 19) | (src[e] << 3) | et[e];
        lr[i] = atomicAdd(&lhist[cc[i]], 1);
      } else {
        cc[i] = -1;
      }
    }
    __syncthreads();
    if (tid < NBKT && lhist[tid] > 0) lbase[tid] = atomicAdd(&bcur[tid], lhist[tid]);
    __syncthreads();
#pragma unroll
    for (int i = 0; i < 16; ++i)
      if (cc[i] >= 0) ebuf[lbase[cc[i]] + lr[i]] = rec[i];
    return;
  }

  const int id = blockIdx.x - (doCsr ? CSR_BLOCKS : 0);
  const int x = id & 7, j = id >> 3;
  const int tile = (j / 9) * 8 + x;
  const int cb = j % 9;
  if (tile >= NTILES) return;
  const int row0 = tile * 128;

  const int lane = tid & 63;
  const int w = tid >> 6;
  const int i16 = lane & 15, q = lane >> 4;
  const int mbase = (w & 1) * 64, nbase = (w >> 1) * 64;

  uint4 va[8], vb[8];
#pragma unroll
  for (int i = 0; i < 8; ++i) {
    int L = tid + i * 256;
    int r = L >> 4, c4 = L & 15;
    int agr = row0 + r; if (agr >= NNODES) agr = NNODES - 1;
    va[i] = *(const uint4*)(A + (size_t)agr * F + c4 * 8);
    vb[i] = *(const uint4*)(Wt + ((size_t)cb * 128 + r) * F + c4 * 8);
  }
#pragma unroll
  for (int i = 0; i < 8; ++i) {
    int L = tid + i * 256;
    int r = L >> 4, c4 = L & 15;
    int sidx = r * 16 + (c4 ^ (r & 15));
    As[sidx] = va[i];
    Bs[sidx] = vb[i];
  }
  __syncthreads();

  f32x4 acc[4][4];
#pragma unroll
  for (int a = 0; a < 4; ++a)
#pragma unroll
    for (int b = 0; b < 4; ++b) acc[a][b] = (f32x4)0.f;

#pragma unroll
  for (int c = 0; c < 4; ++c) {
    bf16x8 af[4], bfr[4];
#pragma unroll
    for (int mi = 0; mi < 4; ++mi) {
      int r = mbase + mi * 16 + i16;
      af[mi] = *(const bf16x8*)&As[r * 16 + ((c * 4 + q) ^ (r & 15))];
    }
#pragma unroll
    for (int ni = 0; ni < 4; ++ni) {
      int r = nbase + ni * 16 + i16;
      bfr[ni] = *(const bf16x8*)&Bs[r * 16 + ((c * 4 + q) ^ (r & 15))];
    }
    // Swapped operands: D[m=weight feature][n=node row]
#pragma unroll
    for (int mi = 0; mi < 4; ++mi)
#pragma unroll
      for (int ni = 0; ni < 4; ++ni)
        acc[mi][ni] = __builtin_amdgcn_mfma_f32_16x16x32_bf16(
            bfr[ni], af[mi], acc[mi][ni], 0, 0, 0);
  }

  // Epilogue: lane holds rows (node) = row0+mbase+mi*16+i16,
  // cols (feature) = cb*128 + nbase + ni*16 + q*4 + [0..3] -> 4 fp8 -> uint.
#pragma unroll
  for (int mi = 0; mi < 4; ++mi) {
    int row = row0 + mbase + mi * 16 + i16;
    bool ok = row < NNODES;
    size_t rb = (size_t)row * NOUT + cb * 128 + nbase + q * 4;
#pragma unroll
    for (int ni = 0; ni < 4; ++ni) {
      f32x4 v = acc[mi][ni];
      unsigned pk = 0;
      pk = __builtin_amdgcn_cvt_pk_fp8_f32(v[0], v[1], pk, false);
      pk = __builtin_amdgcn_cvt_pk_fp8_f32(v[2], v[3], pk, true);
      if (ok) *(unsigned*)(xrs + rb + ni * 16) = pk;
    }
  }
}

// ========== aggregate: h_next[dst] = relu(sum_e xrs[edata] + self + b) ======
__global__ __launch_bounds__(256)
void k_aggregate(const unsigned char* __restrict__ xrs,
                 const int* __restrict__ rowptr, const int* __restrict__ edata,
                 const float* __restrict__ bias, ushort* __restrict__ hout) {
  int node = (blockIdx.x * 256 + threadIdx.x) >> 6;
  int lane = threadIdx.x & 63;
  if (node >= NNODES) return;
  int beg = rowptr[node], end = rowptr[node + 1];

  unsigned sv = ((const ushort*)(xrs + (size_t)node * NOUT + NREL * F))[lane];
  f32x2 sf = __builtin_amdgcn_cvt_pk_f32_fp8(sv, false);
  float ax = sf[0], ay = sf[1];

  for (int base = beg; base < end; base += 64) {
    int cnt = end - base; if (cnt > 64) cnt = 64;
    int my = (base + lane < end) ? edata[base + lane] : 0;
    int e = 0;
    for (; e + 16 <= cnt; e += 16) {
      unsigned v[16];
#pragma unroll
      for (int k = 0; k < 16; ++k)
        v[k] = ((const ushort*)(xrs + (size_t)__builtin_amdgcn_readlane(my, e + k)))[lane];
#pragma unroll
      for (int k = 0; k < 16; ++k) {
        f32x2 f = __builtin_amdgcn_cvt_pk_f32_fp8(v[k], false);
        ax += f[0]; ay += f[1];
      }
    }
    for (; e + 4 <= cnt; e += 4) {
      unsigned v[4];
#pragma unroll
      for (int k = 0; k < 4; ++k)
        v[k] = ((const ushort*)(xrs + (size_t)__builtin_amdgcn_readlane(my, e + k)))[lane];
#pragma unroll
      for (int k = 0; k < 4; ++k) {
        f32x2 f = __builtin_amdgcn_cvt_pk_f32_fp8(v[k], false);
        ax += f[0]; ay += f[1];
      }
    }
    for (; e < cnt; ++e) {
      unsigned vv = ((const ushort*)(xrs + (size_t)__builtin_amdgcn_readlane(my, e)))[lane];
      f32x2 f = __builtin_amdgcn_cvt_pk_f32_fp8(vv, false);
      ax += f[0]; ay += f[1];
    }
  }

  float2 bb = ((const float2*)bias)[lane];
  ax = fmaxf(ax + bb.x, 0.f);
  ay = fmaxf(ay + bb.y, 0.f);
  ((unsigned*)(hout + (size_t)node * F))[lane] = f2bf(ax) | (f2bf(ay) << 16);
}

// ============ mean-pool + final fc fused (completion counter) ===============
__global__ __launch_bounds__(256)
void k_colsum_fc(const ushort* __restrict__ h2, float* __restrict__ pooled,
                 unsigned* __restrict__ counter, const float* __restrict__ fcw,
                 const float* __restrict__ fcb, float* __restrict__ out) {
  __shared__ float red[4][128];
  __shared__ unsigned lastFlag;
  const int j = threadIdx.x & 63;
  const int wv = threadIdx.x >> 6;
  float sx = 0.f, sy = 0.f;
  for (int r0 = blockIdx.x * 16 + wv * 4; r0 < NNODES; r0 += gridDim.x * 16) {
    const unsigned* p = (const unsigned*)h2 + (size_t)r0 * 64 + j;
    unsigned v0 = p[0];
    unsigned v1 = (r0 + 1 < NNODES) ? p[64] : 0;
    unsigned v2 = (r0 + 2 < NNODES) ? p[128] : 0;
    unsigned v3 = (r0 + 3 < NNODES) ? p[192] : 0;
    sx += bf2f(v0 & 0xffffu) + bf2f(v1 & 0xffffu) +
          bf2f(v2 & 0xffffu) + bf2f(v3 & 0xffffu);
    sy += bf2f(v0 >> 16) + bf2f(v1 >> 16) + bf2f(v2 >> 16) + bf2f(v3 >> 16);
  }
  red[wv][2 * j] = sx;
  red[wv][2 * j + 1] = sy;
  __syncthreads();
  if (threadIdx.x < 128) {
    float s = red[0][threadIdx.x] + red[1][threadIdx.x] +
              red[2][threadIdx.x] + red[3][threadIdx.x];
    atomicAdd(&pooled[threadIdx.x], s);
  }
  __syncthreads();
  if (threadIdx.x == 0) {
    __threadfence();
    lastFlag = (atomicAdd(counter, 1u) == (unsigned)gridDim.x - 1u) ? 1u : 0u;
  }
  __syncthreads();
  if (lastFlag) {
    __shared__ float sred[128];
    int t = threadIdx.x;
    if (t < 128)
      sred[t] = atomicAdd(&pooled[t], 0.0f) * (1.0f / (float)NNODES) * fcw[t];
    __syncthreads();
    if (t == 0) {
      float v = 0.f;
      for (int i = 0; i < 128; ++i) v += sred[i];
      v += fcb[0];
      out[0] = 1.f / (1.f + expf(-v));
    }
  }
}

// ============================================================================
extern "C" void kernel_launch(void* const* d_in, const int* in_sizes, int n_in,
                              void* d_out, int out_size, void* d_ws, size_t ws_size,
                              hipStream_t stream) {
  const float* in_feat = (const float*)d_in[0];
  const float* W1      = (const float*)d_in[1];
  const float* W1s     = (const float*)d_in[2];
  const float* b1      = (const float*)d_in[3];
  const float* W2      = (const float*)d_in[4];
  const float* W2s     = (const float*)d_in[5];
  const float* b2      = (const float*)d_in[6];
  const float* fcw     = (const float*)d_in[7];
  const float* fcb     = (const float*)d_in[8];
  const int*   src     = (const int*)d_in[9];
  const int*   dst     = (const int*)d_in[10];
  const int*   et      = (const int*)d_in[11];
  float* out = (float*)d_out;

  // Workspace (~110 MB)
  unsigned char* xrs = (unsigned char*)d_ws;              // [50000][1152] fp8
  ushort* feat0 = (ushort*)(xrs + (size_t)NNODES * NOUT); // [50000][128] bf16
  ushort* h1    = feat0 + (size_t)NNODES * F;             // [50000][128]
  ushort* h2    = h1 + (size_t)NNODES * F;                // [50000][128]
  ushort* Wt1   = h2 + (size_t)NNODES * F;                // [1152][128]
  ushort* Wt2   = Wt1 + (size_t)NOUT * F;                 // [1152][128]
  float*    pooled  = (float*)(Wt2 + (size_t)NOUT * F);   // [128]   } one
  unsigned* counter = (unsigned*)(pooled + 128);          // [1]     } memset
  int*      bcnt    = (int*)(counter + 1);                // [NBKT]  } region
  int*   rowptr = bcnt + NBKT;                            // [NNODES+1]
  int*   bbase  = rowptr + NNODES + 2;                    // [NBKT]
  int*   bcur   = bbase + NBKT;                           // [NBKT]
  int*   ebuf   = bcur + NBKT + 1;                        // [NEDGES]
  int*   edata  = ebuf + NEDGES;                          // [NEDGES]

  // single memset: pooled + counter + bcnt
  hipMemsetAsync(pooled, 0, (128 + 1 + NBKT) * sizeof(float), stream);

  // fused prep: coarse hist | feat cvt | weight prep x2
  k_prep<<<PREP_CHIST + PREP_CVT + 2 * PREP_W, 256, 0, stream>>>(
      dst, bcnt, in_feat, feat0, W1, W1s, Wt1, W2, W2s, Wt2);
  k_cscan<<<1, 128, 0, stream>>>(bcnt, bbase, bcur, rowptr);

  const int aggBlocks = (NNODES * 64 + 255) / 256;     // 12500

  // Layer 1 GEMM with CSR-scatter fused (scatter hidden under GEMM)
  gemm_xrs<<<CSR_BLOCKS + GEMM_BLOCKS, 256, 0, stream>>>(
      feat0, Wt1, xrs, 1, src, dst, et, bcur, ebuf);
  k_fsort<<<NBKT, 256, 0, stream>>>(ebuf, bbase, bcnt, rowptr, edata);
  k_aggregate<<<aggBlocks, 256, 0, stream>>>(xrs, rowptr, edata, b1, h1);
  // Layer 2
  gemm_xrs<<<GEMM_BLOCKS, 256, 0, stream>>>(
      h1, Wt2, xrs, 0, src, dst, et, bcur, ebuf);
  k_aggregate<<<aggBlocks, 256, 0, stream>>>(xrs, rowptr, edata, b2, h2);

  // Mean-pool + fc + sigmoid (fused, completion-counter)
  k_colsum_fc<<<784, 256, 0, stream>>>(h2, pooled, counter, fcw, fcb, out);
}